// Round 11
// baseline (31.718 us; speedup 1.0000x reference)
//
#include <hip/hip_runtime.h>

#define B_ 4
#define N_ 256
#define D_ 256
#define L_ 256
#define H_ 128
// PAIR_DIM = 2*D + 3 + L = 771; W1 rows: [0,256)=Wi, [256,512)=Wj,
// [512,515)=Wrel, [515,771)=Wlang
#define NB1_ 16   // rows per block in kernel 1 (16 blocks/batch -> 64 blocks)
#define G1_  4    // d-groups in kernel 1 (64 d each)
#define NB2_ 4    // rows per block in kernel 2
#define TPB_ 1024

// ---------------------------------------------------------------------------
// Kernel 1: per-row precompute, 64 blocks x 16 rows.
//   Aout[b,n,h] = s_i + cproj
//   Bt[b,h,n]   = s_j - cproj + s_lang + b1
// Thread (g, s, h): g = t>>8 covers d in [g*64,(g+1)*64); s = half (8 rows);
// h = column. W1 read once per (g,s) pair -> 2x in-block redundancy only.
// ---------------------------------------------------------------------------
__global__ __launch_bounds__(TPB_) void precomp_kernel(
    const float* __restrict__ feat,     // (B,N,D)
    const float* __restrict__ lang,     // (B,L)
    const float* __restrict__ centers,  // (B,N,3)
    const float* __restrict__ W1,       // (771,H)
    const float* __restrict__ b1,       // (H)
    float* __restrict__ Aout,           // (B,N,H)
    float* __restrict__ Bt)             // (B,H,N)
{
    __shared__ __align__(16) float fs[NB1_][D_];   // 16 KB
    __shared__ __align__(16) float ls[L_];         // 1 KB
    __shared__ float cs[NB1_][3];
    __shared__ float red[G1_][2][17][H_];          // 69.6 KB

    const int bpb = N_ / NB1_;             // 16 blocks per batch
    const int b  = blockIdx.x / bpb;
    const int n0 = (blockIdx.x % bpb) * NB1_;
    const int t  = threadIdx.x;
    const int g  = t >> 8;                 // 0..3
    const int c  = t & 255;
    const int s  = c >> 7;                 // 0..1 (row half, wave-uniform)
    const int h  = c & (H_ - 1);           // 0..127

    for (int i = t; i < NB1_ * D_; i += TPB_) {
        int r = i >> 8, d = i & (D_ - 1);
        fs[r][d] = feat[((b * N_) + (n0 + r)) * D_ + d];
    }
    if (t < L_) ls[t] = lang[b * L_ + t];
    if (t < NB1_ * 3) {
        int r = t / 3, cc = t % 3;
        cs[r][cc] = centers[((b * N_) + (n0 + r)) * 3 + cc] * 0.2f;  // /5
    }
    __syncthreads();

    {
        float si[8] = {0,0,0,0,0,0,0,0};
        float sj[8] = {0,0,0,0,0,0,0,0};
        float sl = 0.f;
        const int r0 = s * 8;              // this thread's 8 rows
        const float* __restrict__ Wi = W1 + h;
        const float* __restrict__ Wj = W1 + D_ * H_ + h;
        const float* __restrict__ Wl = W1 + (2 * D_ + 3) * H_ + h;

        const int d0 = g * (D_ / G1_);     // 64-wide slice
        for (int dd = d0; dd < d0 + D_ / G1_; dd += 4) {
            float wi[4], wj[4], wl[4];
#pragma unroll
            for (int k = 0; k < 4; ++k) {  // independent L2 loads first
                wi[k] = Wi[(dd + k) * H_];
                wj[k] = Wj[(dd + k) * H_];
            }
            if (s == 0) {                  // wave-uniform branch
#pragma unroll
                for (int k = 0; k < 4; ++k) wl[k] = Wl[(dd + k) * H_];
                const float4 lv = *(const float4*)&ls[dd];
                sl += lv.x * wl[0] + lv.y * wl[1] + lv.z * wl[2] + lv.w * wl[3];
            }
#pragma unroll
            for (int r = 0; r < 8; ++r) {
                const float4 fv = *(const float4*)&fs[r0 + r][dd];
                si[r] += fv.x * wi[0] + fv.y * wi[1] + fv.z * wi[2] + fv.w * wi[3];
                sj[r] += fv.x * wj[0] + fv.y * wj[1] + fv.z * wj[2] + fv.w * wj[3];
            }
        }

#pragma unroll
        for (int r = 0; r < 8; ++r) {
            red[g][s][r][h]     = si[r];
            red[g][s][8 + r][h] = sj[r];
        }
        if (s == 0) red[g][0][16][h] = sl;
    }
    __syncthreads();

    if (t < 256) {                          // epilogue: (s2, h) handles 8 rows
        const int h2 = t & (H_ - 1);
        const int s2 = t >> 7;
        float sit[8], sjt[8], slt = 0.f;
#pragma unroll
        for (int r = 0; r < 8; ++r) { sit[r] = 0.f; sjt[r] = 0.f; }
#pragma unroll
        for (int gg = 0; gg < G1_; ++gg) {
#pragma unroll
            for (int r = 0; r < 8; ++r) {
                sit[r] += red[gg][s2][r][h2];
                sjt[r] += red[gg][s2][8 + r][h2];
            }
            slt += red[gg][0][16][h2];
        }
        const float wr0 = W1[(2 * D_ + 0) * H_ + h2];
        const float wr1 = W1[(2 * D_ + 1) * H_ + h2];
        const float wr2 = W1[(2 * D_ + 2) * H_ + h2];
        const float bb  = b1[h2];
        float bt8[8];
#pragma unroll
        for (int r = 0; r < 8; ++r) {
            const int rr = s2 * 8 + r;
            float srel = cs[rr][0] * wr0 + cs[rr][1] * wr1 + cs[rr][2] * wr2;
            Aout[((b * N_) + (n0 + rr)) * H_ + h2] = sit[r] + srel;
            bt8[r] = sjt[r] - srel + slt + bb;
        }
        float* btp = &Bt[((size_t)(b * H_) + h2) * N_ + n0 + s2 * 8];
        *(float4*)btp       = make_float4(bt8[0], bt8[1], bt8[2], bt8[3]);
        *(float4*)(btp + 4) = make_float4(bt8[4], bt8[5], bt8[6], bt8[7]);
    }
}

// ---------------------------------------------------------------------------
// Kernel 2: one block per (b, 4-row n-tile). 1024 threads: t = q*256 + j.
// Quarter q covers h in [q*32,(q+1)*32) for scores, jj in [q*64,(q+1)*64)
// for context. Plain cached loads (kernel boundary flushed Bt/Aout).
// ---------------------------------------------------------------------------
__global__ __launch_bounds__(TPB_) void pair_kernel(
    const float* __restrict__ feat,   // (B,N,D)
    const float* __restrict__ Aout,   // (B,N,H)
    const float* __restrict__ Bt,     // (B,H,N)
    const float* __restrict__ W2,     // (H)
    const float* __restrict__ b2,     // (1)
    const unsigned char* __restrict__ mraw,  // (B,N) bool byte or int32
    float* __restrict__ outEnh,       // (B,N,D)
    float* __restrict__ outW)         // (B,N,N)
{
    __shared__ __align__(16) float As[NB2_][H_];   // 2 KB
    __shared__ __align__(16) float W2s[H_];        // 0.5 KB
    __shared__ float part[4][NB2_][N_];            // 16 KB
    __shared__ float wsh[NB2_][N_];                // 4 KB
    __shared__ unsigned char msk[N_];
    __shared__ int layoutByte;

    const int tiles = N_ / NB2_;           // 64
    const int b  = blockIdx.x / tiles;
    const int n0 = (blockIdx.x % tiles) * NB2_;
    const int t  = threadIdx.x;
    const int q  = t >> 8;                 // 0..3
    const int j  = t & (N_ - 1);           // 0..255

    if (t == 0) layoutByte = 0;
    __syncthreads();

    // layout sniff: under int32 layout all bytes at offset%4!=0 are zero
    if (t < 256) {
        uchar4 v = ((const uchar4*)mraw)[t];   // covers B_*N_ bytes
        if (v.y | v.z | v.w) layoutByte = 1;   // benign same-value race
    }
    if (t < NB2_ * H_) {                       // 512 threads: As rows
        int r = t >> 7, h = t & (H_ - 1);
        As[r][h] = Aout[((b * N_) + (n0 + r)) * H_ + h];
    } else if (t < NB2_ * H_ + H_) {
        W2s[t - NB2_ * H_] = W2[t - NB2_ * H_];
    }
    __syncthreads();

    if (t < N_) {
        msk[t] = layoutByte ? (mraw[b * N_ + t] != 0)
                            : (((const int*)mraw)[b * N_ + t] != 0);
    }
    const float b2v = b2[0];
    __syncthreads();

    // ---- scores: quarter q covers 32 h-rows of the Bt panel ----
    {
        const float* __restrict__ btp =
            Bt + ((size_t)(b * H_) + q * 32) * N_ + j;
        float acc[NB2_] = {0.f, 0.f, 0.f, 0.f};
        for (int hh = 0; hh < 32; hh += 4) {
            float bt0 = btp[(hh + 0) * N_];
            float bt1 = btp[(hh + 1) * N_];
            float bt2 = btp[(hh + 2) * N_];
            float bt3 = btp[(hh + 3) * N_];
            const float4 w2v = *(const float4*)&W2s[q * 32 + hh];
#pragma unroll
            for (int r = 0; r < NB2_; ++r) {
                const float4 av = *(const float4*)&As[r][q * 32 + hh];
                acc[r] += fmaxf(av.x + bt0, 0.f) * w2v.x
                        + fmaxf(av.y + bt1, 0.f) * w2v.y
                        + fmaxf(av.z + bt2, 0.f) * w2v.z
                        + fmaxf(av.w + bt3, 0.f) * w2v.w;
            }
        }
#pragma unroll
        for (int r = 0; r < NB2_; ++r) part[q][r][j] = acc[r];
    }
    __syncthreads();

    // ---- softmax: wave r (of 16) handles row r ----
    {
        const int wid = t >> 6, lane = t & 63;
        if (wid < NB2_) {
            const int r = wid;
            float sc[4], mx = -1e30f;
#pragma unroll
            for (int k = 0; k < 4; ++k) {
                int jj = lane + k * 64;
                float sv = part[0][r][jj] + part[1][r][jj] +
                           part[2][r][jj] + part[3][r][jj] + b2v;
                if (!(msk[n0 + r] && msk[jj])) sv = -1e9f;
                sc[k] = sv;
                mx = fmaxf(mx, sv);
            }
            for (int off = 32; off >= 1; off >>= 1)
                mx = fmaxf(mx, __shfl_xor(mx, off));
            float e[4], sm = 0.f;
#pragma unroll
            for (int k = 0; k < 4; ++k) { e[k] = __expf(sc[k] - mx); sm += e[k]; }
            for (int off = 32; off >= 1; off >>= 1) sm += __shfl_xor(sm, off);
            const float inv = 1.f / sm;
#pragma unroll
            for (int k = 0; k < 4; ++k) {
                int jj = lane + k * 64;
                float w = e[k] * inv;
                wsh[r][jj] = w;
                outW[(((size_t)(b * N_) + (n0 + r)) * N_) + jj] = w;
            }
        }
    }
    __syncthreads();

    // ---- context: quarter q covers 64 jj-rows of feat[b] ----
    {
        const float* __restrict__ fb = feat + (size_t)b * N_ * D_;
        const int d = j;
        float facc[NB2_] = {0.f, 0.f, 0.f, 0.f};
        for (int jj = q * 64; jj < q * 64 + 64; jj += 4) {
            float f0 = fb[(jj + 0) * D_ + d];
            float f1 = fb[(jj + 1) * D_ + d];
            float f2 = fb[(jj + 2) * D_ + d];
            float f3 = fb[(jj + 3) * D_ + d];
#pragma unroll
            for (int r = 0; r < NB2_; ++r) {
                const float4 wv = *(const float4*)&wsh[r][jj];
                facc[r] += wv.x * f0 + wv.y * f1 + wv.z * f2 + wv.w * f3;
            }
        }
        __syncthreads();   // all part reads (softmax) done; reuse part
#pragma unroll
        for (int r = 0; r < NB2_; ++r) part[q][r][d] = facc[r];
    }
    __syncthreads();

    if (t < N_) {
        const float* __restrict__ fb = feat + (size_t)b * N_ * D_;
        const int d = t;
#pragma unroll
        for (int r = 0; r < NB2_; ++r) {
            float v = part[0][r][d] + part[1][r][d] +
                      part[2][r][d] + part[3][r][d] + fb[(n0 + r) * D_ + d];
            outEnh[((b * N_) + (n0 + r)) * D_ + d] = v;
        }
    }
}

// ---------------------------------------------------------------------------
extern "C" void kernel_launch(void* const* d_in, const int* in_sizes, int n_in,
                              void* d_out, int out_size, void* d_ws, size_t ws_size,
                              hipStream_t stream) {
    const float* feat    = (const float*)d_in[0];
    const float* lang    = (const float*)d_in[1];
    const float* centers = (const float*)d_in[2];
    const unsigned char* mraw = (const unsigned char*)d_in[3];
    const float* W1      = (const float*)d_in[4];
    const float* b1      = (const float*)d_in[5];
    const float* W2      = (const float*)d_in[6];
    const float* b2      = (const float*)d_in[7];

    float* outEnh = (float*)d_out;                        // (B,N,D)
    float* outW   = (float*)d_out + (size_t)B_ * N_ * D_; // (B,N,N)

    float* Aout = (float*)d_ws;                           // B*N*H floats
    float* Bt   = Aout + (size_t)B_ * N_ * H_;            // B*H*N floats

    precomp_kernel<<<B_ * N_ / NB1_, TPB_, 0, stream>>>(feat, lang, centers,
                                                        W1, b1, Aout, Bt);
    pair_kernel<<<B_ * N_ / NB2_, TPB_, 0, stream>>>(feat, Aout, Bt, W2, b2,
                                                     mraw, outEnh, outW);
}